// Round 16
// baseline (193.766 us; speedup 1.0000x reference)
//
#include <hip/hip_runtime.h>

typedef _Float16 half8_t __attribute__((ext_vector_type(8)));
typedef float    f32x4_t __attribute__((ext_vector_type(4)));
typedef unsigned int uint4_t __attribute__((ext_vector_type(4)));

#define OUT_HALF 1351680   // 4096*330
#define NDE 330

// ws layout (bytes): only x16 is used now (prep_all eliminated in v14)
#define OFF_X16 0u

#define C_LOG2E 1.44269504088896f
#define C_LN2   0.69314718055995f

__device__ __forceinline__ float fast_softplus(float x) {
    float e = __builtin_amdgcn_exp2f(x * 1.44269504f);
    return __builtin_amdgcn_logf(1.0f + e) * 0.69314718f;
}

// g(u) = u * rcp(1 + exp2(-u)); with u = log2e*t this equals log2e*silu(t).
// log2e folded into W1,b1,b2; ln2 into W3; W2 unchanged (log2e*ln2 == 1).
// MINIMUM-ISSUE-SLOT formulation: 4 VALU slots/element (exp2, add, rcp, mul)
// + 1 cvt/pair. r10 rejected Newton-rcp (+31us, issue-slot bound); r12
// verified folding (-9us); r14 rejected kf-unroll 2 (+9us). This body is
// the measured local optimum.
__device__ __forceinline__ unsigned pk_g(float u0, float u1) {
    float e0 = __builtin_amdgcn_exp2f(-u0);   // neg is a free src modifier
    float e1 = __builtin_amdgcn_exp2f(-u1);
    float g0 = u0 * __builtin_amdgcn_rcpf(1.0f + e0);
    float g1 = u1 * __builtin_amdgcn_rcpf(1.0f + e1);
    return __builtin_bit_cast(unsigned, __builtin_amdgcn_cvt_pkrtz(g0, g1));
}

// ---- x prep: f32 [4096][40] -> f16 [4096][64] (cols 40=1.0 bias, 41+ = 0)
__global__ __launch_bounds__(256) void prep_x_kernel(const float* __restrict__ x,
                                                     _Float16* __restrict__ x16) {
    int idx = blockIdx.x * 256 + threadIdx.x;
    if (idx >= 4096 * 64) return;
    int b = idx >> 6, cc = idx & 63;
    float v = (cc < 40) ? x[b * 40 + cc] : (cc == 40 ? 1.0f : 0.0f);
    x16[idx] = (_Float16)v;
}

// ---- fused 3-layer ensemble MLP, v14:
// v13 (round 15: mlp 116us w/ fused transpose, total 190us) with the
// SEPARATE PREP KERNEL DELETED. Measurement across all 16 rounds shows a
// constant ~74-79us of non-mlp time; transpose removal bought only ~3us,
// so prep_all (3994 blocks, ~35MB f32 read + 18MB half write, serialized
// before mlp) + its launch gap is the dominant overhead. The weight
// fragment-pack now happens INLINE in each mlp block's staging phase
// (straight from f32 — the former fallback path, layouts identical incl.
// log2e/ln2 folding): ~80KB f32 reads per block, L2-served after the first
// block of each de (all 64 blocks of a de sit on one XCD: de = xcd*42+grp),
// plus ~50 one-time cvt insts/thread. Launches drop 3 -> 2.
// mlp body and all verified-optimal choices unchanged: (512,4), unroll 1,
// strided bases, rcp-silu, fused transposed output.
__global__ __launch_bounds__(512, 4) void mlp_kernel(
    const _Float16* __restrict__ x16,
    const float* __restrict__ W1, const float* __restrict__ b1,
    const float* __restrict__ W2, const float* __restrict__ b2,
    const float* __restrict__ W3, const float* __restrict__ b3,
    float* __restrict__ out)
{
    __shared__ _Float16 w1s[8192];        // W1 A-fragments (b1 folded), 16 KB
    __shared__ _Float16 w2s[16384];       // W2 fragment-linear, 32 KB
    __shared__ _Float16 w3s[2048];        // layer-3 A fragments, 4 KB
    __shared__ float    b2s[128];

    const int bid   = blockIdx.x;
    // de-RANGE per XCD: xcd = bid&7 owns de in [xcd*42, xcd*42+42).
    const int grp   = bid >> 6;            // 0..41
    const int xcd   = bid & 7;
    const int chunk = (bid >> 3) & 7;
    const int de    = xcd * 42 + grp;
    if (de >= NDE) return;   // whole block exits together (no barrier hazard)

    const int tid  = threadIdx.x;       // 0..511 (8 waves)
    const int wave = tid >> 6;
    const int lane = tid & 63;
    const int c    = lane & 15;
    const int q    = lane >> 4;

    // ---- inline pack: W1 + W2 + W3 + b2 from f32 into LDS fragment layouts
    {
        const float* W1g = W1 + (size_t)de * (128 * 40);
        const float* b1g = b1 + (size_t)de * 128;
        for (int s = tid; s < 1024; s += 512) {
            int ht = s >> 7, rem = s & 127, kff = rem >> 6, ln = rem & 63;
            int cc = ln & 15, qq = ln >> 4, h = ht * 16 + cc;
            union { _Float16 hh[8]; half8_t v; } u;
            if (kff == 0) {
                f32x4_t a  = *(const f32x4_t*)&W1g[h * 40 + qq * 8];
                f32x4_t bb = *(const f32x4_t*)&W1g[h * 40 + qq * 8 + 4];
                #pragma unroll
                for (int r = 0; r < 4; r++) {
                    u.hh[r]     = (_Float16)(a[r]  * C_LOG2E);
                    u.hh[4 + r] = (_Float16)(bb[r] * C_LOG2E);
                }
            } else {
                #pragma unroll
                for (int r = 0; r < 8; r++) u.hh[r] = (_Float16)0.0f;
                if (qq == 0) {
                    f32x4_t a  = *(const f32x4_t*)&W1g[h * 40 + 32];
                    f32x4_t bb = *(const f32x4_t*)&W1g[h * 40 + 36];
                    #pragma unroll
                    for (int r = 0; r < 4; r++) {
                        u.hh[r]     = (_Float16)(a[r]  * C_LOG2E);
                        u.hh[4 + r] = (_Float16)(bb[r] * C_LOG2E);
                    }
                } else if (qq == 1) {
                    u.hh[0] = (_Float16)(b1g[h] * C_LOG2E);
                }
            }
            *(half8_t*)&w1s[(ht * 2 + kff) * 512 + ln * 8] = u.v;
        }
    }
    {
        const float* W2g = W2 + (size_t)de * 16384;
        #pragma unroll
        for (int i0 = 0; i0 < 4; i0++) {
            int i = tid + i0 * 512;         // fragment-linear index
            int F = i >> 6, l = i & 63;     // F = mt*4+kf
            int mt = F >> 2, kf = F & 3, q2 = l >> 4, c2 = l & 15;
            int g = mt * 16 + c2;
            f32x4_t a  = *(const f32x4_t*)&W2g[g * 128 + kf * 32 + q2 * 4];
            f32x4_t bb = *(const f32x4_t*)&W2g[g * 128 + kf * 32 + 16 + q2 * 4];
            union { _Float16 hh[8]; half8_t v; } u;
            #pragma unroll
            for (int r = 0; r < 4; r++) { u.hh[r] = (_Float16)a[r]; u.hh[4 + r] = (_Float16)bb[r]; }
            *(half8_t*)&w2s[i * 8] = u.v;
        }
    }
    if (tid < 256) {
        const float* W3g = W3 + (size_t)de * 256;
        int kf = tid >> 6, ln = tid & 63, c2 = ln & 15, q2 = ln >> 4;
        union { _Float16 hh[8]; half8_t v; } u;
        #pragma unroll
        for (int r = 0; r < 8; r++) u.hh[r] = (_Float16)0.0f;
        if (c2 < 2) {
            #pragma unroll
            for (int r = 0; r < 4; r++) {
                u.hh[r]     = (_Float16)(W3g[c2 * 128 + kf * 32 + q2 * 4 + r]      * C_LN2);
                u.hh[4 + r] = (_Float16)(W3g[c2 * 128 + kf * 32 + 16 + q2 * 4 + r] * C_LN2);
            }
        }
        *(half8_t*)&w3s[kf * 512 + ln * 8] = u.v;
    }
    if (tid < 128) b2s[tid] = b2[de * 128 + tid] * C_LOG2E;
    __syncthreads();

    const float b3m = b3[de * 2 + 0];   // uniform -> SGPRs
    const float b3l = b3[de * 2 + 1];
    const f32x4_t zero4 = {0.f, 0.f, 0.f, 0.f};

    // lane-dependent bases, computed once; hot-loop reads are base + imm.
    const _Float16* const w1base = w1s + lane * 8;
    const _Float16* const w2base = w2s + lane * 8;
    const _Float16* const w3base = w3s + lane * 8;
    const float*    const b2base = b2s + q * 4;

    // each wave owns 16 rows per iteration; 8 waves x 16 x 4 its = 512 rows
    const int r0 = chunk * 512 + wave * 16 + c;
    const _Float16* px = x16 + (size_t)r0 * 64 + q * 8;
    // transposed direct output: row-major [4096][330], column de
    float* po = out + (size_t)r0 * 330 + de;

    #pragma unroll 1
    for (int it = 0; it < 4; it++) {
        half8_t xf0 = *(const half8_t*)(px);
        half8_t xf1 = *(const half8_t*)(px + 32);

        f32x4_t acc2[8];
        #pragma unroll
        for (int mt = 0; mt < 8; mt++)
            acc2[mt] = *(const f32x4_t*)(b2base + mt * 16);

        // ---- interleaved layer1 -> layer2, strided bases, imm offsets
        const _Float16* pw1 = w1base;   // +2048 halves per kf
        const _Float16* paf = w2base;   // +512 halves per kf
        #pragma unroll 1
        for (int kf = 0; kf < 4; kf++) {
            uint4_t bu;
            #pragma unroll
            for (int h2 = 0; h2 < 2; h2++) {
                half8_t a0 = *(const half8_t*)(pw1 + h2 * 1024);
                half8_t a1 = *(const half8_t*)(pw1 + h2 * 1024 + 512);
                f32x4_t a = __builtin_amdgcn_mfma_f32_16x16x32_f16(a0, xf0, zero4, 0, 0, 0);
                f32x4_t t = __builtin_amdgcn_mfma_f32_16x16x32_f16(a1, xf1, a, 0, 0, 0);
                bu[2 * h2 + 0] = pk_g(t[0], t[1]);
                bu[2 * h2 + 1] = pk_g(t[2], t[3]);
            }
            const half8_t bh = __builtin_bit_cast(half8_t, bu);
            #pragma unroll
            for (int mt = 0; mt < 8; mt++) {
                half8_t af = *(const half8_t*)(paf + mt * 2048);
                acc2[mt] = __builtin_amdgcn_mfma_f32_16x16x32_f16(af, bh, acc2[mt], 0, 0, 0);
            }
            pw1 += 2048;
            paf += 512;
        }

        // ---- interleaved layer2-silu -> layer3
        f32x4_t acc3 = zero4;
        #pragma unroll
        for (int kf2 = 0; kf2 < 4; kf2++) {
            half8_t w3f = *(const half8_t*)(w3base + kf2 * 512);
            uint4_t bu;
            bu[0] = pk_g(acc2[kf2 * 2 + 0][0], acc2[kf2 * 2 + 0][1]);
            bu[1] = pk_g(acc2[kf2 * 2 + 0][2], acc2[kf2 * 2 + 0][3]);
            bu[2] = pk_g(acc2[kf2 * 2 + 1][0], acc2[kf2 * 2 + 1][1]);
            bu[3] = pk_g(acc2[kf2 * 2 + 1][2], acc2[kf2 * 2 + 1][3]);
            acc3 = __builtin_amdgcn_mfma_f32_16x16x32_f16(
                w3f, __builtin_bit_cast(half8_t, bu), acc3, 0, 0, 0);
        }

        if (q == 0) {
            float vm = acc3[0] + b3m;
            float vl = acc3[1] + b3l;
            vl = 5.0f - fast_softplus(5.0f - vl);
            vl = -10.0f + fast_softplus(vl + 10.0f);
            po[0] = vm;               // mean[row][de]
            po[OUT_HALF] = vl;        // logvar[row][de]
        }
        px += 128 * 64;   // next 128-row slab
        po += 128 * 330;
    }
}

extern "C" void kernel_launch(void* const* d_in, const int* in_sizes, int n_in,
                              void* d_out, int out_size, void* d_ws, size_t ws_size,
                              hipStream_t stream) {
    (void)in_sizes; (void)n_in; (void)out_size; (void)ws_size;
    const float* x  = (const float*)d_in[0];
    const float* W1 = (const float*)d_in[1];
    const float* b1 = (const float*)d_in[2];
    const float* W2 = (const float*)d_in[3];
    const float* b2 = (const float*)d_in[4];
    const float* W3 = (const float*)d_in[5];
    const float* b3 = (const float*)d_in[6];
    float* out = (float*)d_out;

    char* ws = (char*)d_ws;
    _Float16* x16 = (_Float16*)(ws + OFF_X16);

    // 42 groups x 64 blocks: de = (bid&7)*42 + (bid>>6), chunk = (bid>>3)&7
    const int MLP_GRID = 42 * 64;

    hipLaunchKernelGGL(prep_x_kernel, dim3(1024), dim3(256), 0, stream, x, x16);
    hipLaunchKernelGGL(mlp_kernel, dim3(MLP_GRID), dim3(512), 0, stream,
                       x16, W1, b1, W2, b2, W3, b3, out);
}

// Round 17
// 190.210 us; speedup vs baseline: 1.0187x; 1.0187x over previous
//
#include <hip/hip_runtime.h>

typedef _Float16 half8_t __attribute__((ext_vector_type(8)));
typedef float    f32x4_t __attribute__((ext_vector_type(4)));
typedef unsigned int uint4_t __attribute__((ext_vector_type(4)));

#define OUT_HALF 1351680   // 4096*330
#define NDE 330

// ws layout (bytes)
#define OFF_X16    0u
#define OFF_W1H    11337728u   // 330*8192 halves  (W1 frags, b1 folded, x log2e)
#define OFF_W3H    16744448u   // 330*2048 halves  (W3 frags, x ln2)
#define OFF_W2H    18096128u   // 330*16384 halves (W2 fragment-linear, unscaled)
#define WS_PACKED_BYTES 28909568u

#define C_LOG2E 1.44269504088896f
#define C_LN2   0.69314718055995f

__device__ __forceinline__ float fast_softplus(float x) {
    float e = __builtin_amdgcn_exp2f(x * 1.44269504f);
    return __builtin_amdgcn_logf(1.0f + e) * 0.69314718f;
}

// g(u) = u * rcp(1 + exp2(-u)); with u = log2e*t this equals log2e*silu(t).
// log2e folded into W1,b1,b2; ln2 into W3; W2 unchanged (log2e*ln2 == 1).
// MINIMUM-ISSUE-SLOT formulation: 4 VALU slots/element (exp2, add, rcp, mul)
// + 1 cvt/pair. r10 rejected Newton-rcp (+31us, issue-slot bound); r12
// verified folding (-9us); r14 rejected kf-unroll 2 (+9us); r16 rejected
// inline weight-pack (+14us mlp). This configuration is the measured
// optimum: MfmaUtil + VALUBusy ~ 99% (CU issue slots saturated).
__device__ __forceinline__ unsigned pk_g(float u0, float u1) {
    float e0 = __builtin_amdgcn_exp2f(-u0);   // neg is a free src modifier
    float e1 = __builtin_amdgcn_exp2f(-u1);
    float g0 = u0 * __builtin_amdgcn_rcpf(1.0f + e0);
    float g1 = u1 * __builtin_amdgcn_rcpf(1.0f + e1);
    return __builtin_bit_cast(unsigned, __builtin_amdgcn_cvt_pkrtz(g0, g1));
}

// ---- x prep only (fallback path)
__global__ __launch_bounds__(256) void prep_x_kernel(const float* __restrict__ x,
                                                     _Float16* __restrict__ x16) {
    int idx = blockIdx.x * 256 + threadIdx.x;
    if (idx >= 4096 * 64) return;
    int b = idx >> 6, cc = idx & 63;
    float v = (cc < 40) ? x[b * 40 + cc] : (cc == 40 ? 1.0f : 0.0f);
    x16[idx] = (_Float16)v;
}

// ---- combined prep: x16 + W1/W3 fragment pack (scaled) + W2 fragment-linear
__global__ __launch_bounds__(256) void prep_all_kernel(
    const float* __restrict__ x,
    const float* __restrict__ W1, const float* __restrict__ b1,
    const float* __restrict__ W2, const float* __restrict__ W3,
    _Float16* __restrict__ x16, _Float16* __restrict__ w1h,
    _Float16* __restrict__ w2h, _Float16* __restrict__ w3h)
{
    const int blk = blockIdx.x;
    const int tid = threadIdx.x;
    if (blk < 1024) {
        int idx = blk * 256 + tid;
        int b = idx >> 6, cc = idx & 63;
        float v = (cc < 40) ? x[b * 40 + cc] : (cc == 40 ? 1.0f : 0.0f);
        x16[idx] = (_Float16)v;
        return;
    }
    if (blk < 1024 + NDE) {
        const int de = blk - 1024;
        const float* W1g = W1 + (size_t)de * (128 * 40);
        const float* b1g = b1 + (size_t)de * 128;
        const float* W3g = W3 + (size_t)de * 256;
        for (int s = tid; s < 1024; s += 256) {
            int ht = s >> 7, rem = s & 127, kf = rem >> 6, lane = rem & 63;
            int c = lane & 15, q = lane >> 4, h = ht * 16 + c;
            union { _Float16 hh[8]; half8_t v; } u;
            if (kf == 0) {
                f32x4_t a  = *(const f32x4_t*)&W1g[h * 40 + q * 8];
                f32x4_t bb = *(const f32x4_t*)&W1g[h * 40 + q * 8 + 4];
                #pragma unroll
                for (int r = 0; r < 4; r++) {
                    u.hh[r]     = (_Float16)(a[r]  * C_LOG2E);
                    u.hh[4 + r] = (_Float16)(bb[r] * C_LOG2E);
                }
            } else {
                #pragma unroll
                for (int r = 0; r < 8; r++) u.hh[r] = (_Float16)0.0f;
                if (q == 0) {
                    f32x4_t a  = *(const f32x4_t*)&W1g[h * 40 + 32];
                    f32x4_t bb = *(const f32x4_t*)&W1g[h * 40 + 36];
                    #pragma unroll
                    for (int r = 0; r < 4; r++) {
                        u.hh[r]     = (_Float16)(a[r]  * C_LOG2E);
                        u.hh[4 + r] = (_Float16)(bb[r] * C_LOG2E);
                    }
                } else if (q == 1) {
                    u.hh[0] = (_Float16)(b1g[h] * C_LOG2E);
                }
            }
            *(half8_t*)&w1h[(size_t)de * 8192 + (ht * 2 + kf) * 512 + lane * 8] = u.v;
        }
        if (tid < 256) {
            int kf = tid >> 6, lane = tid & 63, c = lane & 15, q = lane >> 4;
            union { _Float16 hh[8]; half8_t v; } u;
            #pragma unroll
            for (int r = 0; r < 8; r++) u.hh[r] = (_Float16)0.0f;
            if (c < 2) {
                #pragma unroll
                for (int r = 0; r < 4; r++) {
                    u.hh[r]     = (_Float16)(W3g[c * 128 + kf * 32 + q * 4 + r]      * C_LN2);
                    u.hh[4 + r] = (_Float16)(W3g[c * 128 + kf * 32 + 16 + q * 4 + r] * C_LN2);
                }
            }
            *(half8_t*)&w3h[(size_t)de * 2048 + kf * 512 + lane * 8] = u.v;
        }
        return;
    }
    // W2: fragment-linear layout [mt*4+kf][q*16+c][8]: the mlp af read is a
    // lane-linear 16B LDS read (conflict-free) and staging is a linear copy.
    // Values unscaled (log2e * ln2 == 1 cancellation).
    int f = (blk - 1024 - NDE) * 256 + tid;
    if (f >= NDE * 2048) return;
    int de = f >> 11, i = f & 2047;
    int g = i >> 4, kf = (i >> 2) & 3, qq = i & 3;
    const float* W2g = W2 + (size_t)de * 16384;
    f32x4_t a  = *(const f32x4_t*)&W2g[g * 128 + kf * 32 + qq * 4];
    f32x4_t bb = *(const f32x4_t*)&W2g[g * 128 + kf * 32 + 16 + qq * 4];
    union { _Float16 hh[8]; half8_t v; } u;
    #pragma unroll
    for (int r = 0; r < 4; r++) { u.hh[r] = (_Float16)a[r]; u.hh[4 + r] = (_Float16)bb[r]; }
    int off = (((g >> 4) * 4 + kf) * 64 + qq * 16 + (g & 15)) * 8;
    *(half8_t*)&w2h[(size_t)de * 16384 + off] = u.v;
}

// ---- fused 3-layer ensemble MLP, v15 == v13 (round-15 config, 190.3us,
// session best — byte-identical revert after r16's inline-pack regression):
// mlp body = v10 (verified local optimum across 6 axes), fused transposed
// output with de = xcd*42 + grp so all 16 de of a 64B output line sit on
// one XCD (L2 line-merge: WRITE 23.5MB, 2.2x, acceptable). 2 launches.
// Counters at this config: MfmaUtil+VALUBusy ~ 99% — CU issue saturated.
template <bool PACKED>
__global__ __launch_bounds__(512, 4) void mlp_kernel(
    const _Float16* __restrict__ x16,
    const float* __restrict__ W1, const float* __restrict__ b1,
    const float* __restrict__ W2, const float* __restrict__ b2,
    const float* __restrict__ W3, const float* __restrict__ b3,
    const _Float16* __restrict__ w1h, const _Float16* __restrict__ w2h,
    const _Float16* __restrict__ w3h,
    float* __restrict__ out)
{
    __shared__ _Float16 w1s[8192];        // W1 A-fragments (b1 folded), 16 KB
    __shared__ _Float16 w2s[16384];       // W2 fragment-linear, 32 KB
    __shared__ _Float16 w3s[2048];        // layer-3 A fragments, 4 KB
    __shared__ float    b2s[128];

    const int bid   = blockIdx.x;
    // de-RANGE per XCD: xcd = bid&7 owns de in [xcd*42, xcd*42+42).
    const int grp   = bid >> 6;            // 0..41
    const int xcd   = bid & 7;
    const int chunk = (bid >> 3) & 7;
    const int de    = xcd * 42 + grp;
    if (de >= NDE) return;   // whole block exits together (no barrier hazard)

    const int tid  = threadIdx.x;       // 0..511 (8 waves)
    const int wave = tid >> 6;
    const int lane = tid & 63;
    const int c    = lane & 15;
    const int q    = lane >> 4;

    // ---- stage W1 + W2 + W3 + b2 into LDS (one copy for all 8 waves)
    if constexpr (PACKED) {
        const _Float16* W1g = w1h + (size_t)de * 8192;
        *(half8_t*)&w1s[tid * 8]         = *(const half8_t*)&W1g[tid * 8];
        *(half8_t*)&w1s[(tid + 512) * 8] = *(const half8_t*)&W1g[(tid + 512) * 8];
        const _Float16* W2g = w2h + (size_t)de * 16384;
        #pragma unroll
        for (int i0 = 0; i0 < 4; i0++) {
            int i = tid + i0 * 512;
            *(half8_t*)&w2s[i * 8] = *(const half8_t*)&W2g[i * 8];
        }
        if (tid < 256)
            *(half8_t*)&w3s[tid * 8] = *(const half8_t*)&w3h[(size_t)de * 2048 + tid * 8];
    } else {
        // build W1 fragment layout from f32 (scaled by log2e, b1 folded)
        {
            const float* W1g = W1 + (size_t)de * (128 * 40);
            const float* b1g = b1 + (size_t)de * 128;
            for (int s = tid; s < 1024; s += 512) {
                int ht = s >> 7, rem = s & 127, kff = rem >> 6, ln = rem & 63;
                int cc = ln & 15, qq = ln >> 4, h = ht * 16 + cc;
                union { _Float16 hh[8]; half8_t v; } u;
                if (kff == 0) {
                    f32x4_t a  = *(const f32x4_t*)&W1g[h * 40 + qq * 8];
                    f32x4_t bb = *(const f32x4_t*)&W1g[h * 40 + qq * 8 + 4];
                    #pragma unroll
                    for (int r = 0; r < 4; r++) {
                        u.hh[r]     = (_Float16)(a[r]  * C_LOG2E);
                        u.hh[4 + r] = (_Float16)(bb[r] * C_LOG2E);
                    }
                } else {
                    #pragma unroll
                    for (int r = 0; r < 8; r++) u.hh[r] = (_Float16)0.0f;
                    if (qq == 0) {
                        f32x4_t a  = *(const f32x4_t*)&W1g[h * 40 + 32];
                        f32x4_t bb = *(const f32x4_t*)&W1g[h * 40 + 36];
                        #pragma unroll
                        for (int r = 0; r < 4; r++) {
                            u.hh[r]     = (_Float16)(a[r]  * C_LOG2E);
                            u.hh[4 + r] = (_Float16)(bb[r] * C_LOG2E);
                        }
                    } else if (qq == 1) {
                        u.hh[0] = (_Float16)(b1g[h] * C_LOG2E);
                    }
                }
                *(half8_t*)&w1s[(ht * 2 + kff) * 512 + ln * 8] = u.v;
            }
        }
        const float* W2g = W2 + (size_t)de * 16384;
        #pragma unroll
        for (int i0 = 0; i0 < 4; i0++) {
            int i = tid + i0 * 512;         // fragment-linear index
            int F = i >> 6, l = i & 63;     // F = mt*4+kf
            int mt = F >> 2, kf = F & 3, q2 = l >> 4, c2 = l & 15;
            int g = mt * 16 + c2;
            f32x4_t a  = *(const f32x4_t*)&W2g[g * 128 + kf * 32 + q2 * 4];
            f32x4_t bb = *(const f32x4_t*)&W2g[g * 128 + kf * 32 + 16 + q2 * 4];
            union { _Float16 hh[8]; half8_t v; } u;
            #pragma unroll
            for (int r = 0; r < 4; r++) { u.hh[r] = (_Float16)a[r]; u.hh[4 + r] = (_Float16)bb[r]; }
            *(half8_t*)&w2s[i * 8] = u.v;
        }
        if (tid < 256) {
            const float* W3g = W3 + (size_t)de * 256;
            int kf = tid >> 6, ln = tid & 63, c2 = ln & 15, q2 = ln >> 4;
            union { _Float16 hh[8]; half8_t v; } u;
            #pragma unroll
            for (int r = 0; r < 8; r++) u.hh[r] = (_Float16)0.0f;
            if (c2 < 2) {
                #pragma unroll
                for (int r = 0; r < 4; r++) {
                    u.hh[r]     = (_Float16)(W3g[c2 * 128 + kf * 32 + q2 * 4 + r]      * C_LN2);
                    u.hh[4 + r] = (_Float16)(W3g[c2 * 128 + kf * 32 + 16 + q2 * 4 + r] * C_LN2);
                }
            }
            *(half8_t*)&w3s[kf * 512 + ln * 8] = u.v;
        }
    }
    if (tid < 128) b2s[tid] = b2[de * 128 + tid] * C_LOG2E;
    __syncthreads();

    const float b3m = b3[de * 2 + 0];   // uniform -> SGPRs
    const float b3l = b3[de * 2 + 1];
    const f32x4_t zero4 = {0.f, 0.f, 0.f, 0.f};

    // lane-dependent bases, computed once; hot-loop reads are base + imm.
    const _Float16* const w1base = w1s + lane * 8;
    const _Float16* const w2base = w2s + lane * 8;
    const _Float16* const w3base = w3s + lane * 8;
    const float*    const b2base = b2s + q * 4;

    // each wave owns 16 rows per iteration; 8 waves x 16 x 4 its = 512 rows
    const int r0 = chunk * 512 + wave * 16 + c;
    const _Float16* px = x16 + (size_t)r0 * 64 + q * 8;
    // transposed direct output: row-major [4096][330], column de
    float* po = out + (size_t)r0 * 330 + de;

    #pragma unroll 1
    for (int it = 0; it < 4; it++) {
        half8_t xf0 = *(const half8_t*)(px);
        half8_t xf1 = *(const half8_t*)(px + 32);

        f32x4_t acc2[8];
        #pragma unroll
        for (int mt = 0; mt < 8; mt++)
            acc2[mt] = *(const f32x4_t*)(b2base + mt * 16);

        // ---- interleaved layer1 -> layer2, strided bases, imm offsets
        const _Float16* pw1 = w1base;   // +2048 halves per kf
        const _Float16* paf = w2base;   // +512 halves per kf
        #pragma unroll 1
        for (int kf = 0; kf < 4; kf++) {
            uint4_t bu;
            #pragma unroll
            for (int h2 = 0; h2 < 2; h2++) {
                half8_t a0 = *(const half8_t*)(pw1 + h2 * 1024);
                half8_t a1 = *(const half8_t*)(pw1 + h2 * 1024 + 512);
                f32x4_t a = __builtin_amdgcn_mfma_f32_16x16x32_f16(a0, xf0, zero4, 0, 0, 0);
                f32x4_t t = __builtin_amdgcn_mfma_f32_16x16x32_f16(a1, xf1, a, 0, 0, 0);
                bu[2 * h2 + 0] = pk_g(t[0], t[1]);
                bu[2 * h2 + 1] = pk_g(t[2], t[3]);
            }
            const half8_t bh = __builtin_bit_cast(half8_t, bu);
            #pragma unroll
            for (int mt = 0; mt < 8; mt++) {
                half8_t af = *(const half8_t*)(paf + mt * 2048);
                acc2[mt] = __builtin_amdgcn_mfma_f32_16x16x32_f16(af, bh, acc2[mt], 0, 0, 0);
            }
            pw1 += 2048;
            paf += 512;
        }

        // ---- interleaved layer2-silu -> layer3
        f32x4_t acc3 = zero4;
        #pragma unroll
        for (int kf2 = 0; kf2 < 4; kf2++) {
            half8_t w3f = *(const half8_t*)(w3base + kf2 * 512);
            uint4_t bu;
            bu[0] = pk_g(acc2[kf2 * 2 + 0][0], acc2[kf2 * 2 + 0][1]);
            bu[1] = pk_g(acc2[kf2 * 2 + 0][2], acc2[kf2 * 2 + 0][3]);
            bu[2] = pk_g(acc2[kf2 * 2 + 1][0], acc2[kf2 * 2 + 1][1]);
            bu[3] = pk_g(acc2[kf2 * 2 + 1][2], acc2[kf2 * 2 + 1][3]);
            acc3 = __builtin_amdgcn_mfma_f32_16x16x32_f16(
                w3f, __builtin_bit_cast(half8_t, bu), acc3, 0, 0, 0);
        }

        if (q == 0) {
            float vm = acc3[0] + b3m;
            float vl = acc3[1] + b3l;
            vl = 5.0f - fast_softplus(5.0f - vl);
            vl = -10.0f + fast_softplus(vl + 10.0f);
            po[0] = vm;               // mean[row][de]
            po[OUT_HALF] = vl;        // logvar[row][de]
        }
        px += 128 * 64;   // next 128-row slab
        po += 128 * 330;
    }
}

extern "C" void kernel_launch(void* const* d_in, const int* in_sizes, int n_in,
                              void* d_out, int out_size, void* d_ws, size_t ws_size,
                              hipStream_t stream) {
    (void)in_sizes; (void)n_in; (void)out_size;
    const float* x  = (const float*)d_in[0];
    const float* W1 = (const float*)d_in[1];
    const float* b1 = (const float*)d_in[2];
    const float* W2 = (const float*)d_in[3];
    const float* b2 = (const float*)d_in[4];
    const float* W3 = (const float*)d_in[5];
    const float* b3 = (const float*)d_in[6];
    float* out = (float*)d_out;

    char* ws = (char*)d_ws;
    _Float16* x16 = (_Float16*)(ws + OFF_X16);

    // 42 groups x 64 blocks: de = (bid&7)*42 + (bid>>6), chunk = (bid>>3)&7
    const int MLP_GRID = 42 * 64;

    if (ws_size >= WS_PACKED_BYTES) {
        _Float16* w1h = (_Float16*)(ws + OFF_W1H);
        _Float16* w3h = (_Float16*)(ws + OFF_W3H);
        _Float16* w2h = (_Float16*)(ws + OFF_W2H);
        hipLaunchKernelGGL(prep_all_kernel, dim3(1024 + NDE + 2640), dim3(256), 0, stream,
                           x, W1, b1, W2, W3, x16, w1h, w2h, w3h);
        hipLaunchKernelGGL((mlp_kernel<true>), dim3(MLP_GRID), dim3(512), 0, stream,
                           x16, W1, b1, W2, b2, W3, b3, w1h, w2h, w3h, out);
    } else {
        hipLaunchKernelGGL(prep_x_kernel, dim3(1024), dim3(256), 0, stream, x, x16);
        hipLaunchKernelGGL((mlp_kernel<false>), dim3(MLP_GRID), dim3(512), 0, stream,
                           x16, W1, b1, W2, b2, W3, b3, x16, x16, x16, out);
    }
}